// Round 2
// baseline (470.745 us; speedup 1.0000x reference)
//
#include <hip/hip_runtime.h>
#include <math.h>

// ---------------------------------------------------------------------------
// ActorNetwork forward, MI355X (gfx950). Round 3: split env GEMM out of the
// fused kernel. Diagnosis: fused k_main was HBM-latency-bound (1-deep reg
// prefetch => ~1.3 KB in flight/CU => 0.9 TB/s). k_env streams state1 via
// global_load_lds double-buffered 16 KB chunks (16 KB in flight per block,
// 4 blocks/CU) => HBM-bound. k_rest = old k_main minus env phase; env_e is
// imported as ready-made A-frags from workspace.
// Shapes: B=65536, N=8, OBS0=6, OBS1=1024, OBS2=7, H=64, HC=128, NA=2.
// ---------------------------------------------------------------------------

typedef float f32x4 __attribute__((ext_vector_type(4)));
typedef float f32x4u __attribute__((ext_vector_type(4), aligned(4)));
typedef float f32x2u __attribute__((ext_vector_type(2), aligned(4)));
typedef __bf16 bf16x8 __attribute__((ext_vector_type(8)));
typedef unsigned short u16x8 __attribute__((ext_vector_type(8)));

#define DI __device__ __forceinline__

DI unsigned short f2bf_u(float f) {  // fp32 -> bf16 bits, RTNE (epilogues)
  unsigned u = __builtin_bit_cast(unsigned, f);
  u += 0x7fffu + ((u >> 16) & 1u);
  return (unsigned short)(u >> 16);
}
DI float bfu2f(unsigned short s) {
  unsigned u = ((unsigned)s) << 16;
  return __builtin_bit_cast(float, u);
}
DI u16x8 cvt8(f32x4 x, f32x4 y) {  // native cvt (v_cvt_pk_bf16_f32 on gfx950)
  bf16x8 r;
  r[0] = (__bf16)x[0]; r[1] = (__bf16)x[1]; r[2] = (__bf16)x[2]; r[3] = (__bf16)x[3];
  r[4] = (__bf16)y[0]; r[5] = (__bf16)y[1]; r[6] = (__bf16)y[2]; r[7] = (__bf16)y[3];
  return __builtin_bit_cast(u16x8, r);
}
DI f32x4 mfma16(u16x8 a, u16x8 b, f32x4 c) {
  return __builtin_amdgcn_mfma_f32_16x16x32_bf16(
      __builtin_bit_cast(bf16x8, a), __builtin_bit_cast(bf16x8, b), c, 0, 0, 0);
}
DI void gload_lds16(const void* g, void* l) {  // async global->LDS, 16 B/lane
  typedef __attribute__((address_space(1))) const unsigned GU;
  typedef __attribute__((address_space(3))) unsigned LU;
  __builtin_amdgcn_global_load_lds((GU*)g, (LU*)l, 16, 0, 0);
}

// Fragment layouts (learn_hip m89/m91):
//   A-frag: lane l holds A[m = l&15][k = (l>>4)*8 + j], j=0..7
//   B-frag: lane l holds B[k = (l>>4)*8 + j][n = l&15]
//   C/D   : lane l holds C[row = (l>>4)*4 + ri][col = l&15]
// Packed frag buffers: u16x8[(kt*NT + nt)*64 + lane].

// ---- workspace layout (bytes) ----
constexpr size_t WS_WGF = 0;        // Wg frags  [32kt][4nt]   131072
constexpr size_t WS_WS2 = 131072;   // Ws2 frags [2][4]          8192
constexpr size_t WS_WV  = 139264;   // Wv frags  [2][4]          8192
constexpr size_t WS_MQK = 147456;   // Mqk frags [2][4]          8192
constexpr size_t WS_WC1 = 155648;   // Wc1 frags [6][8]         49152
constexpr size_t WS_WC2 = 204800;   // Wc2 frags [4][8]         32768
constexpr size_t WS_ENV = 237568;   // env_e A-frags [4096mt][2kt][64]  8388608

// ---------------------------------------------------------------------------
// k_prep: pack all weights into bf16 B-frag layout; M_qk computed inline.
// ---------------------------------------------------------------------------
__global__ __launch_bounds__(256) void k_prep(
    const float* __restrict__ Wg, const float* __restrict__ Ws2,
    const float* __restrict__ Wv, const float* __restrict__ Wq,
    const float* __restrict__ Wk, const float* __restrict__ Wc1,
    const float* __restrict__ Wc2,
    unsigned short* __restrict__ wgf, unsigned short* __restrict__ ws2f,
    unsigned short* __restrict__ wvf, unsigned short* __restrict__ mqkf,
    unsigned short* __restrict__ wc1f, unsigned short* __restrict__ wc2f) {
  const int idx = blockIdx.x * 256 + threadIdx.x;  // 118784 total
  const float* src = nullptr;
  unsigned short* dst;
  int i, ntm, NC;
  bool is_mqk = false;
  if (idx < 65536)      { src = Wg;  dst = wgf;  i = idx;          ntm = 2; NC = 64;  }
  else if (idx < 69632) { src = Ws2; dst = ws2f; i = idx - 65536;  ntm = 2; NC = 64;  }
  else if (idx < 73728) { src = Wv;  dst = wvf;  i = idx - 69632;  ntm = 2; NC = 64;  }
  else if (idx < 77824) { is_mqk = true; dst = mqkf; i = idx - 73728; ntm = 2; NC = 64; }
  else if (idx < 102400){ src = Wc1; dst = wc1f; i = idx - 77824;  ntm = 3; NC = 128; }
  else                  { src = Wc2; dst = wc2f; i = idx - 102400; ntm = 3; NC = 128; }
  const int j = i & 7, ln = (i >> 3) & 63, t2 = i >> 9;
  const int nt = t2 & ((1 << ntm) - 1), kt = t2 >> ntm;
  const int k = kt * 32 + (ln >> 4) * 8 + j, n = nt * 16 + (ln & 15);
  float val;
  if (is_mqk) {  // M_qk[k][n] = dot(Wq[k,:], Wk[n,:])
    const f32x4* qp = (const f32x4*)(Wq + k * 64);
    const f32x4* kp = (const f32x4*)(Wk + n * 64);
    float acc = 0.f;
#pragma unroll
    for (int d4 = 0; d4 < 16; ++d4) {
      const f32x4 a = qp[d4], b = kp[d4];
#pragma unroll
      for (int e = 0; e < 4; ++e) acc = fmaf(a[e], b[e], acc);
    }
    val = acc;
  } else {
    val = src[k * NC + n];
  }
  dst[i] = f2bf_u(val);
}

// ---------------------------------------------------------------------------
// k_env: env_e = relu(state1 @ Wg + bg), streamed.  32 rows/block, K=1024 in
// 8 chunks of 128 cols staged to LDS via global_load_lds (16 KB per chunk,
// double-buffered => 16 KB in flight per block, 4 blocks/CU). A-tile LDS is
// XOR-swizzled (pre-swizzled global source + swizzled ds_read; rule #21) to
// kill the 16-way bank conflict of row-major [32][128] fp32 column reads.
// Wave w: m-tile (w&1), n-pair (w>>1); full-K accumulate (no split-K reduce).
// Output written directly in A-frag layout (ready for k_rest's concat tile).
// LDS 36864 B -> 4 blocks/CU.
// ---------------------------------------------------------------------------
__global__ __launch_bounds__(256, 4) void k_env(
    const float* __restrict__ s1, const unsigned short* __restrict__ wgf,
    const float* __restrict__ bg, unsigned short* __restrict__ envf) {
  __shared__ __align__(16) char smem[36864];  // [2][16384] A bufs + 4096 STG
  unsigned short* STGs = (unsigned short*)(smem + 32768);
  u16x8* STG = (u16x8*)(smem + 32768);

  const int tid = threadIdx.x;
  const int lane = tid & 63, wave = tid >> 6;
  const int lo = lane & 15, q = lane >> 4;
  const int bbase = blockIdx.x * 32;
  const int mt = wave & 1, ntb = wave >> 1;  // m-tile, n-pair (=kt of frag)

  const char* s1b = (const char*)(s1 + (size_t)bbase * 1024);

  // staging geometry: thread stages 4x16B per chunk; LDS dest is linear
  // (wave-uniform base + lane*16, required by global_load_lds), global source
  // carries the inverse swizzle: col ^= (row&7)<<4 within the 512 B row.
  int srow[4], scol[4];
#pragma unroll
  for (int i = 0; i < 4; ++i) {
    const int T = (i * 256 + tid) * 16;
    srow[i] = T >> 9;
    scol[i] = (T & 511) ^ ((srow[i] & 7) << 4);
  }
  auto stage = [&](char* dst, int c) {
    const int srcb = c * 512;  // chunk base within the 4096 B row
#pragma unroll
    for (int i = 0; i < 4; ++i)
      gload_lds16(s1b + (size_t)srow[i] * 4096 + srcb + scol[i],
                  dst + (i * 256 + tid) * 16);
  };

  f32x4 acc0 = {}, acc1 = {};
  const int row = mt * 16 + lo;
  const int sw = (row & 7) << 4;
  const u16x8* wgfp = (const u16x8*)wgf + (ntb * 2) * 64 + lane;

  auto compute = [&](const char* src, int c) {
#pragma unroll
    for (int kt = 0; kt < 4; ++kt) {
      const int base = row * 512 + kt * 128 + q * 32;
      const f32x4 alo = *(const f32x4*)(src + (base ^ sw));
      const f32x4 ahi = *(const f32x4*)(src + ((base + 16) ^ sw));
      const int ktg = c * 4 + kt;
      const u16x8 b0 = wgfp[(ktg * 4 + 0) * 64];
      const u16x8 b1 = wgfp[(ktg * 4 + 1) * 64];
      const u16x8 af = cvt8(alo, ahi);
      acc0 = mfma16(af, b0, acc0);
      acc1 = mfma16(af, b1, acc1);
    }
  };

  stage(smem, 0);
  __syncthreads();
#pragma unroll
  for (int cc = 0; cc < 4; ++cc) {
    stage(smem + 16384, cc * 2 + 1);   // next chunk in flight across compute
    compute(smem, cc * 2);
    __syncthreads();                   // drains vmcnt: buf1 ready
    if (cc < 3) stage(smem, cc * 2 + 2);
    compute(smem + 16384, cc * 2 + 1);
    __syncthreads();
  }

  // epilogue: bias+relu, transpose C/D layout -> A-frag via LDS (each wave
  // owns exactly frag (mt, kt=ntb); bijective scalar writes), store 16 B/lane.
#pragma unroll
  for (int ni = 0; ni < 2; ++ni) {
    const f32x4 a = ni ? acc1 : acc0;
    const int h = (ntb * 2 + ni) * 16 + lo;  // global col 0..63
    const float bias = bg[h];
#pragma unroll
    for (int ri = 0; ri < 4; ++ri) {
      const float v = fmaxf(a[ri] + bias, 0.f);
      STGs[((mt * 2 + ntb) * 64 + ((((h >> 3) & 3) << 4) | (q * 4 + ri))) * 8 +
           (h & 7)] = f2bf_u(v);
    }
  }
  __syncthreads();
  const u16x8 v = STG[(mt * 2 + ntb) * 64 + lane];
  *((u16x8*)envf + ((size_t)((bbase >> 4) + mt) * 2 + ntb) * 64 + lane) = v;
}

// ---------------------------------------------------------------------------
// k_rest: everything except the env GEMM; 32 batch rows/block, 2048 blocks.
// env_e arrives as ready A-frags from k_env (1 global load + 1 ds_write per
// wave into concat kt 2,3). All other phases identical to the fused kernel.
// ---------------------------------------------------------------------------
__global__ __launch_bounds__(256, 3) void k_rest(
    const float* __restrict__ s0, const float* __restrict__ s2,
    const float* __restrict__ W0, const float* __restrict__ b0v,
    const float* __restrict__ Ws1, const float* __restrict__ bs1,
    const unsigned short* __restrict__ ws2f, const float* __restrict__ bs2,
    const unsigned short* __restrict__ wvf, const unsigned short* __restrict__ mqkf,
    const unsigned short* __restrict__ wc1f, const float* __restrict__ bc1,
    const unsigned short* __restrict__ wc2f, const float* __restrict__ bc2,
    const float* __restrict__ Wc3, const float* __restrict__ bc3,
    const unsigned short* __restrict__ envf,
    float* __restrict__ out) {
  // LDS map (54272 B -> 3 blocks/CU):
  //  [0,32768)     EF  : E1/E2 frags [16mt][2kt][64] u16x8
  //                later: H1F frags [2][4][64] (8 KB) + H2 fp32 [32][132] @+8192
  //  [32768,45056) CF  : concat frags [2mt][6kt][64] (kt 0,1 own; 2,3 env; 4,5 vatt)
  //  [45056,53248) QK  : qk fp32 [32][64]; sE2 frags [2][2][64]
  //  [53248,54272) SC  : scores -> alpha fp32 [256] (softmax in place)
  __shared__ __align__(16) char smem[54272];
  u16x8* EF = (u16x8*)smem;
  unsigned short* EFs = (unsigned short*)smem;
  u16x8* H1F = (u16x8*)smem;
  unsigned short* H1Fs = (unsigned short*)smem;
  float* H2 = (float*)(smem + 8192);
  u16x8* CF = (u16x8*)(smem + 32768);
  float* QK = (float*)(smem + 45056);
  u16x8* SEF = (u16x8*)(smem + 45056);
  float* SC = (float*)(smem + 53248);

  const int tid = threadIdx.x;
  const int lane = tid & 63, wave = tid >> 6;
  const int lo = lane & 15, q = lane >> 4;
  const int bbase = blockIdx.x * 32;

  // ---- env_e frag import (earliest issue; consumed only at D1) ----
  const int emt_ = wave >> 1, ekt = wave & 1;
  const u16x8 ev =
      *((const u16x8*)envf + ((size_t)((bbase >> 4) + emt_) * 2 + ekt) * 64 + lane);

  // ---- early global loads for phases A / C1 ----
  const int bl8 = tid >> 3, n8 = tid & 7;
  const float* s2p = s2 + ((size_t)(bbase + bl8) * 8 + n8) * 7;
  const f32x4u x03 = *(const f32x4u*)s2p;
  const f32x2u x45 = *(const f32x2u*)(s2p + 4);
  const float x6 = s2p[6];
  const float* s0p = s0 + (size_t)(bbase + bl8) * 6;
  const f32x4u y03 = *(const f32x4u*)s0p;
  const f32x2u y45 = *(const f32x2u*)(s0p + 4);

  CF[(emt_ * 6 + 2 + ekt) * 64 + lane] = ev;  // concat kt 2,3 (env_e)
  // (no barrier: phase A touches only EF; CF fenced by later syncs before D1)

  // ---- Phase A: E1 = relu(state2 @ Ws1 + bs1), K=7 fp32 VALU; mask ----
  bool maskreg;
  {
    float xv[7] = {x03[0], x03[1], x03[2], x03[3], x45[0], x45[1], x6};
    const float sum = xv[0] + xv[1] + xv[2] + xv[3] + xv[4] + xv[5] + xv[6];
    maskreg = (sum != 0.f);  // padded slots are exact zeros
    const int mt = tid >> 4, rl = tid & 15;
#pragma unroll
    for (int c = 0; c < 8; ++c) {
      float a[8];
#pragma unroll
      for (int i = 0; i < 8; ++i) a[i] = bs1[c * 8 + i];
#pragma unroll
      for (int j = 0; j < 7; ++j) {
        const float* wr = Ws1 + j * 64 + c * 8;
#pragma unroll
        for (int i = 0; i < 8; ++i) a[i] = fmaf(xv[j], wr[i], a[i]);
      }
      u16x8 pk;
#pragma unroll
      for (int i = 0; i < 8; ++i) pk[i] = f2bf_u(fmaxf(a[i], 0.f));
      EF[(mt * 2 + (c >> 2)) * 64 + (((c & 3) << 4) | rl)] = pk;
    }
  }
  __syncthreads();

  // ---- Phase B: E2 = relu(E1 @ Ws2 + bs2), MFMA, in-place frag overwrite ----
  {
    u16x8 Bf[4][2];
#pragma unroll
    for (int nt = 0; nt < 4; ++nt)
#pragma unroll
      for (int kt = 0; kt < 2; ++kt)
        Bf[nt][kt] = ((const u16x8*)ws2f)[(kt * 4 + nt) * 64 + lane];
    float bias[4];
#pragma unroll
    for (int nt = 0; nt < 4; ++nt) bias[nt] = bs2[nt * 16 + lo];
#pragma unroll
    for (int mi = 0; mi < 4; ++mi) {  // wave owns mtiles wave*4..+3
      const int mt = wave * 4 + mi;
      const u16x8 A0 = EF[(mt * 2 + 0) * 64 + lane];
      const u16x8 A1 = EF[(mt * 2 + 1) * 64 + lane];
      f32x4 acc[4] = {};
#pragma unroll
      for (int nt = 0; nt < 4; ++nt) {
        acc[nt] = mfma16(A0, Bf[nt][0], acc[nt]);
        acc[nt] = mfma16(A1, Bf[nt][1], acc[nt]);
      }
#pragma unroll
      for (int nt = 0; nt < 4; ++nt) {
        const int h = nt * 16 + lo;
#pragma unroll
        for (int ri = 0; ri < 4; ++ri) {
          const float v = fmaxf(acc[nt][ri] + bias[nt], 0.f);
          const int rr = mt * 16 + q * 4 + ri;
          EFs[((mt * 2 + (h >> 5)) * 64 + ((((h >> 3) & 3) << 4) | (rr & 15))) * 8 +
              (h & 7)] = f2bf_u(v);
        }
      }
    }
  }
  __syncthreads();

  // ---- Phase C1: own_e = relu(s0 @ W0 + b0), K=6 VALU -> concat kt 0,1 ----
  {
    const int mt = bl8 >> 4, fl = ((n8 & 3) << 4) | (bl8 & 15), kt = n8 >> 2;
    const float yv[6] = {y03[0], y03[1], y03[2], y03[3], y45[0], y45[1]};
    float a[8];
#pragma unroll
    for (int i = 0; i < 8; ++i) a[i] = b0v[n8 * 8 + i];
#pragma unroll
    for (int j = 0; j < 6; ++j) {
      const float* wr = W0 + j * 64 + n8 * 8;
#pragma unroll
      for (int i = 0; i < 8; ++i) a[i] = fmaf(yv[j], wr[i], a[i]);
    }
    u16x8 pk;
#pragma unroll
    for (int i = 0; i < 8; ++i) pk[i] = f2bf_u(fmaxf(a[i], 0.f));
    CF[(mt * 6 + kt) * 64 + fl] = pk;
  }
  __syncthreads();

  // ---- Phase C2: qk = own_e @ M_qk (MFMA) -> QK fp32 [32][64] ----
  {
#pragma unroll
    for (int pp = 0; pp < 2; ++pp) {
      const int pr = wave * 2 + pp, mt = pr >> 2, nt = pr & 3;
      const u16x8 A0 = CF[(mt * 6 + 0) * 64 + lane];
      const u16x8 A1 = CF[(mt * 6 + 1) * 64 + lane];
      const u16x8 B0 = ((const u16x8*)mqkf)[(0 * 4 + nt) * 64 + lane];
      const u16x8 B1 = ((const u16x8*)mqkf)[(1 * 4 + nt) * 64 + lane];
      f32x4 acc = {};
      acc = mfma16(A0, B0, acc);
      acc = mfma16(A1, B1, acc);
#pragma unroll
      for (int ri = 0; ri < 4; ++ri)
        QK[(mt * 16 + q * 4 + ri) * 64 + nt * 16 + lo] = acc[ri];
    }
  }
  __syncthreads();

  // ---- Phase C3: score_r = (E2_r . qk_b)/8, masked -> SC ----
  {
    const int r = tid, bl = r >> 3, mt = r >> 4, rl = r & 15;
    float dot = 0.f;
#pragma unroll
    for (int c = 0; c < 8; ++c) {
      const u16x8 e = EF[(mt * 2 + (c >> 2)) * 64 + (((c & 3) << 4) | rl)];
      const float* qkp = QK + bl * 64 + c * 8;
      const f32x4 qa = *(const f32x4*)(qkp);
      const f32x4 qb = *(const f32x4*)(qkp + 4);
#pragma unroll
      for (int i = 0; i < 4; ++i) dot = fmaf(bfu2f(e[i]), qa[i], dot);
#pragma unroll
      for (int i = 0; i < 4; ++i) dot = fmaf(bfu2f(e[4 + i]), qb[i], dot);
    }
    SC[r] = maskreg ? dot * 0.125f : -1e30f;  // 1/sqrt(64)
  }
  __syncthreads();

  // ---- Phase C4: softmax over N=8, in place in SC ----
  if (tid < 32) {
    float s[8];
#pragma unroll
    for (int n = 0; n < 8; ++n) s[n] = SC[tid * 8 + n];
    float mx = s[0];
#pragma unroll
    for (int n = 1; n < 8; ++n) mx = fmaxf(mx, s[n]);
    float e[8], sum = 0.f;
#pragma unroll
    for (int n = 0; n < 8; ++n) { e[n] = __expf(s[n] - mx); sum += e[n]; }
    const float inv = 1.f / sum;
#pragma unroll
    for (int n = 0; n < 8; ++n) SC[tid * 8 + n] = e[n] * inv;
  }
  __syncthreads();

  // ---- Phase C5: sE2_b = sum_n alpha_n * E2_{b,n} -> SEF frags ----
  {
    float al[8];
#pragma unroll
    for (int n = 0; n < 8; ++n) al[n] = SC[bl8 * 8 + n];
    float a[8] = {0.f, 0.f, 0.f, 0.f, 0.f, 0.f, 0.f, 0.f};
#pragma unroll
    for (int n = 0; n < 8; ++n) {
      const int rr = bl8 * 8 + n;
      const u16x8 e =
          EF[((rr >> 4) * 2 + (n8 >> 2)) * 64 + (((n8 & 3) << 4) | (rr & 15))];
#pragma unroll
      for (int i = 0; i < 8; ++i) a[i] = fmaf(al[n], bfu2f(e[i]), a[i]);
    }
    u16x8 pk;
#pragma unroll
    for (int i = 0; i < 8; ++i) pk[i] = f2bf_u(a[i]);
    SEF[((bl8 >> 4) * 2 + (n8 >> 2)) * 64 + (((n8 & 3) << 4) | (bl8 & 15))] = pk;
  }
  __syncthreads();

  // ---- Phase C6: v_att = sE2 @ Wv (MFMA) -> concat frags kt 4,5 ----
  {
    unsigned short* CFs = (unsigned short*)CF;
#pragma unroll
    for (int pp = 0; pp < 2; ++pp) {
      const int pr = wave * 2 + pp, mt = pr >> 2, nt = pr & 3;
      const u16x8 A0 = SEF[(mt * 2 + 0) * 64 + lane];
      const u16x8 A1 = SEF[(mt * 2 + 1) * 64 + lane];
      const u16x8 B0 = ((const u16x8*)wvf)[(0 * 4 + nt) * 64 + lane];
      const u16x8 B1 = ((const u16x8*)wvf)[(1 * 4 + nt) * 64 + lane];
      f32x4 acc = {};
      acc = mfma16(A0, B0, acc);
      acc = mfma16(A1, B1, acc);
      const int h = nt * 16 + lo;
#pragma unroll
      for (int ri = 0; ri < 4; ++ri) {
        const int rr = mt * 16 + q * 4 + ri;
        CFs[((mt * 6 + 4 + (h >> 5)) * 64 + ((((h >> 3) & 3) << 4) | (rr & 15))) * 8 +
            (h & 7)] = f2bf_u(acc[ri]);
      }
    }
  }
  __syncthreads();

  // ---- Phase D1: h1 = relu(concat @ Wc1 + bc1), K=192 -> H1F frags ----
  {
    const int mt = wave & 1, ntb = (wave >> 1) * 4;
    u16x8 A[6];
#pragma unroll
    for (int kt = 0; kt < 6; ++kt) A[kt] = CF[(mt * 6 + kt) * 64 + lane];
#pragma unroll
    for (int ni = 0; ni < 4; ++ni) {
      const int nt = ntb + ni;
      f32x4 acc = {};
#pragma unroll
      for (int kt = 0; kt < 6; ++kt) {
        const u16x8 Bf = ((const u16x8*)wc1f)[(kt * 8 + nt) * 64 + lane];
        acc = mfma16(A[kt], Bf, acc);
      }
      const float bias = bc1[nt * 16 + lo];
      const int h = nt * 16 + lo;
#pragma unroll
      for (int ri = 0; ri < 4; ++ri) {
        const float v = fmaxf(acc[ri] + bias, 0.f);
        const int rr = mt * 16 + q * 4 + ri;
        H1Fs[((mt * 4 + (h >> 5)) * 64 + ((((h >> 3) & 3) << 4) | (rr & 15))) * 8 +
             (h & 7)] = f2bf_u(v);
      }
    }
  }
  __syncthreads();

  // ---- Phase D2: h2 = relu(h1 @ Wc2 + bc2) -> H2 fp32 [32][132] ----
  {
    const int mt = wave & 1, ntb = (wave >> 1) * 4;
    u16x8 A[4];
#pragma unroll
    for (int kt = 0; kt < 4; ++kt) A[kt] = H1F[(mt * 4 + kt) * 64 + lane];
#pragma unroll
    for (int ni = 0; ni < 4; ++ni) {
      const int nt = ntb + ni;
      f32x4 acc = {};
#pragma unroll
      for (int kt = 0; kt < 4; ++kt) {
        const u16x8 Bf = ((const u16x8*)wc2f)[(kt * 8 + nt) * 64 + lane];
        acc = mfma16(A[kt], Bf, acc);
      }
      const float bias = bc2[nt * 16 + lo];
#pragma unroll
      for (int ri = 0; ri < 4; ++ri)
        H2[(mt * 16 + q * 4 + ri) * 132 + nt * 16 + lo] =
            fmaxf(acc[ri] + bias, 0.f);
    }
  }
  __syncthreads();

  // ---- Phase D3: out = tanh(h2 @ Wc3 + bc3), fp32, all 256 threads ----
  {
    const int kq = n8 >> 1, a = n8 & 1;  // 4 K-quarters x 2 actions per row
    const f32x4* h4 = (const f32x4*)(H2 + bl8 * 132 + kq * 32);
    const float* wr = Wc3 + kq * 64;  // Wc3[h][2], h = kq*32 + j
    float acc = 0.f;
#pragma unroll
    for (int j4 = 0; j4 < 8; ++j4) {
      const f32x4 hv = h4[j4];
#pragma unroll
      for (int e = 0; e < 4; ++e) acc = fmaf(hv[e], wr[(j4 * 4 + e) * 2 + a], acc);
    }
    acc += __shfl_down(acc, 2);
    acc += __shfl_down(acc, 4);
    if (kq == 0) out[(size_t)(bbase + bl8) * 2 + a] = tanhf(acc + bc3[a]);
  }
}

// ---------------------------------------------------------------------------
extern "C" void kernel_launch(void* const* d_in, const int* in_sizes, int n_in,
                              void* d_out, int out_size, void* d_ws, size_t ws_size,
                              hipStream_t stream) {
  const float* s0  = (const float*)d_in[0];
  const float* s1  = (const float*)d_in[1];
  const float* s2  = (const float*)d_in[2];
  const float* W0  = (const float*)d_in[3];
  const float* b0  = (const float*)d_in[4];
  const float* Wg  = (const float*)d_in[5];
  const float* bg  = (const float*)d_in[6];
  const float* Ws1 = (const float*)d_in[7];
  const float* bs1 = (const float*)d_in[8];
  const float* Ws2 = (const float*)d_in[9];
  const float* bs2 = (const float*)d_in[10];
  const float* Wq  = (const float*)d_in[11];
  const float* Wk  = (const float*)d_in[12];
  const float* Wv  = (const float*)d_in[13];
  const float* Wc1 = (const float*)d_in[14];
  const float* bc1 = (const float*)d_in[15];
  const float* Wc2 = (const float*)d_in[16];
  const float* bc2 = (const float*)d_in[17];
  const float* Wc3 = (const float*)d_in[18];
  const float* bc3 = (const float*)d_in[19];

  char* ws = (char*)d_ws;
  unsigned short* wgf  = (unsigned short*)(ws + WS_WGF);
  unsigned short* ws2f = (unsigned short*)(ws + WS_WS2);
  unsigned short* wvf  = (unsigned short*)(ws + WS_WV);
  unsigned short* mqkf = (unsigned short*)(ws + WS_MQK);
  unsigned short* wc1f = (unsigned short*)(ws + WS_WC1);
  unsigned short* wc2f = (unsigned short*)(ws + WS_WC2);
  unsigned short* envf = (unsigned short*)(ws + WS_ENV);

  hipLaunchKernelGGL(k_prep, dim3(464), dim3(256), 0, stream, Wg, Ws2, Wv, Wq,
                     Wk, Wc1, Wc2, wgf, ws2f, wvf, mqkf, wc1f, wc2f);
  hipLaunchKernelGGL(k_env, dim3(2048), dim3(256), 0, stream, s1, wgf, bg, envf);
  hipLaunchKernelGGL(k_rest, dim3(2048), dim3(256), 0, stream, s0, s2, W0, b0,
                     Ws1, bs1, ws2f, bs2, wvf, mqkf, wc1f, bc1, wc2f, bc2, Wc3,
                     bc3, envf, (float*)d_out);
}

// Round 6
// 453.354 us; speedup vs baseline: 1.0384x; 1.0384x over previous
//
#include <hip/hip_runtime.h>
#include <math.h>

// ---------------------------------------------------------------------------
// ActorNetwork forward, MI355X (gfx950). Round 4: re-fuse env streaming into
// the main kernel. R2 verified the global_load_lds-staged env GEMM (MLP fix:
// 16 KB in flight/block vs ~100 B with reg-pipelining) but the k_env/k_rest
// split ate the gain in launch overhead + envf round-trip (17 MB) + duplicated
// prologue. Here the env staging double-buffer (2x16 KB) lives in the SAME LDS
// bytes the EF frags use afterward -> no LDS growth, 3 blocks/CU, one kernel.
// Shapes: B=65536, N=8, OBS0=6, OBS1=1024, OBS2=7, H=64, HC=128, NA=2.
// ---------------------------------------------------------------------------

typedef float f32x4 __attribute__((ext_vector_type(4)));
typedef float f32x4u __attribute__((ext_vector_type(4), aligned(4)));
typedef float f32x2u __attribute__((ext_vector_type(2), aligned(4)));
typedef __bf16 bf16x8 __attribute__((ext_vector_type(8)));
typedef unsigned short u16x8 __attribute__((ext_vector_type(8)));

#define DI __device__ __forceinline__

DI unsigned short f2bf_u(float f) {  // fp32 -> bf16 bits, RTNE (epilogues)
  unsigned u = __builtin_bit_cast(unsigned, f);
  u += 0x7fffu + ((u >> 16) & 1u);
  return (unsigned short)(u >> 16);
}
DI float bfu2f(unsigned short s) {
  unsigned u = ((unsigned)s) << 16;
  return __builtin_bit_cast(float, u);
}
DI u16x8 cvt8(f32x4 x, f32x4 y) {  // native cvt (v_cvt_pk_bf16_f32 on gfx950)
  bf16x8 r;
  r[0] = (__bf16)x[0]; r[1] = (__bf16)x[1]; r[2] = (__bf16)x[2]; r[3] = (__bf16)x[3];
  r[4] = (__bf16)y[0]; r[5] = (__bf16)y[1]; r[6] = (__bf16)y[2]; r[7] = (__bf16)y[3];
  return __builtin_bit_cast(u16x8, r);
}
DI f32x4 mfma16(u16x8 a, u16x8 b, f32x4 c) {
  return __builtin_amdgcn_mfma_f32_16x16x32_bf16(
      __builtin_bit_cast(bf16x8, a), __builtin_bit_cast(bf16x8, b), c, 0, 0, 0);
}
DI void gload_lds16(const void* g, void* l) {  // async global->LDS, 16 B/lane
  typedef __attribute__((address_space(1))) const unsigned GU;
  typedef __attribute__((address_space(3))) unsigned LU;
  __builtin_amdgcn_global_load_lds((GU*)g, (LU*)l, 16, 0, 0);
}

// Fragment layouts (learn_hip m89/m91):
//   A-frag: lane l holds A[m = l&15][k = (l>>4)*8 + j], j=0..7
//   B-frag: lane l holds B[k = (l>>4)*8 + j][n = l&15]
//   C/D   : lane l holds C[row = (l>>4)*4 + ri][col = l&15]
// Packed frag buffers: u16x8[(kt*NT + nt)*64 + lane].

// ---- workspace layout (bytes) ----
constexpr size_t WS_WGF = 0;        // Wg frags  [32kt][4nt]   131072
constexpr size_t WS_WS2 = 131072;   // Ws2 frags [2][4]          8192
constexpr size_t WS_WV  = 139264;   // Wv frags  [2][4]          8192
constexpr size_t WS_MQK = 147456;   // Mqk frags [2][4]          8192
constexpr size_t WS_WC1 = 155648;   // Wc1 frags [6][8]         49152
constexpr size_t WS_WC2 = 204800;   // Wc2 frags [4][8]         32768

// ---------------------------------------------------------------------------
// k_prep: pack all weights into bf16 B-frag layout; M_qk computed inline.
// ---------------------------------------------------------------------------
__global__ __launch_bounds__(256) void k_prep(
    const float* __restrict__ Wg, const float* __restrict__ Ws2,
    const float* __restrict__ Wv, const float* __restrict__ Wq,
    const float* __restrict__ Wk, const float* __restrict__ Wc1,
    const float* __restrict__ Wc2,
    unsigned short* __restrict__ wgf, unsigned short* __restrict__ ws2f,
    unsigned short* __restrict__ wvf, unsigned short* __restrict__ mqkf,
    unsigned short* __restrict__ wc1f, unsigned short* __restrict__ wc2f) {
  const int idx = blockIdx.x * 256 + threadIdx.x;  // 118784 total
  const float* src = nullptr;
  unsigned short* dst;
  int i, ntm, NC;
  bool is_mqk = false;
  if (idx < 65536)      { src = Wg;  dst = wgf;  i = idx;          ntm = 2; NC = 64;  }
  else if (idx < 69632) { src = Ws2; dst = ws2f; i = idx - 65536;  ntm = 2; NC = 64;  }
  else if (idx < 73728) { src = Wv;  dst = wvf;  i = idx - 69632;  ntm = 2; NC = 64;  }
  else if (idx < 77824) { is_mqk = true; dst = mqkf; i = idx - 73728; ntm = 2; NC = 64; }
  else if (idx < 102400){ src = Wc1; dst = wc1f; i = idx - 77824;  ntm = 3; NC = 128; }
  else                  { src = Wc2; dst = wc2f; i = idx - 102400; ntm = 3; NC = 128; }
  const int j = i & 7, ln = (i >> 3) & 63, t2 = i >> 9;
  const int nt = t2 & ((1 << ntm) - 1), kt = t2 >> ntm;
  const int k = kt * 32 + (ln >> 4) * 8 + j, n = nt * 16 + (ln & 15);
  float val;
  if (is_mqk) {  // M_qk[k][n] = dot(Wq[k,:], Wk[n,:])
    const f32x4* qp = (const f32x4*)(Wq + k * 64);
    const f32x4* kp = (const f32x4*)(Wk + n * 64);
    float acc = 0.f;
#pragma unroll
    for (int d4 = 0; d4 < 16; ++d4) {
      const f32x4 a = qp[d4], b = kp[d4];
#pragma unroll
      for (int e = 0; e < 4; ++e) acc = fmaf(a[e], b[e], acc);
    }
    val = acc;
  } else {
    val = src[k * NC + n];
  }
  dst[i] = f2bf_u(val);
}

// ---------------------------------------------------------------------------
// k_main: whole network for 32 batch rows per block. 2048 blocks x 256 thr.
// Env GEMM streams state1 K=1024 in 8 chunks of 128 cols via global_load_lds
// (16 KB/chunk, double-buffered in the bytes EF occupies later). A-tile is
// XOR-swizzled (pre-swizzled global source + swizzled ds_read; rule #21) to
// kill the bank conflict of row-major [32][128] fp32 column reads. Wave w:
// m-tile (w&1), n-pair (w>>1); full-K accumulate (no split-K reduce); env
// epilogue writes concat frags kt 2,3 directly. All later phases identical
// to the R0-verified kernel. LDS 54272 B -> 3 blocks/CU.
// ---------------------------------------------------------------------------
__global__ __launch_bounds__(256, 3) void k_main(
    const float* __restrict__ s0, const float* __restrict__ s1,
    const float* __restrict__ s2,
    const float* __restrict__ W0, const float* __restrict__ b0v,
    const unsigned short* __restrict__ wgf, const float* __restrict__ bg,
    const float* __restrict__ Ws1, const float* __restrict__ bs1,
    const unsigned short* __restrict__ ws2f, const float* __restrict__ bs2,
    const unsigned short* __restrict__ wvf, const unsigned short* __restrict__ mqkf,
    const unsigned short* __restrict__ wc1f, const float* __restrict__ bc1,
    const unsigned short* __restrict__ wc2f, const float* __restrict__ bc2,
    const float* __restrict__ Wc3, const float* __restrict__ bc3,
    float* __restrict__ out) {
  // LDS map (54272 B -> 3 blocks/CU):
  //  [0,32768)     env staging dbuf [2][16384], then EF: E1/E2 frags
  //                [16mt][2kt][64] u16x8; later H1F frags [2][4][64] (8 KB)
  //                + H2 fp32 [32][132] @+8192
  //  [32768,45056) CF  : concat frags [2mt][6kt][64] (kt 0,1 own; 2,3 env; 4,5 vatt)
  //  [45056,53248) QK  : qk fp32 [32][64]; sE2 frags [2][2][64]
  //  [53248,54272) SC  : scores -> alpha fp32 [256] (softmax in place)
  __shared__ __align__(16) char smem[54272];
  u16x8* EF = (u16x8*)smem;
  unsigned short* EFs = (unsigned short*)smem;
  u16x8* H1F = (u16x8*)smem;
  unsigned short* H1Fs = (unsigned short*)smem;
  float* H2 = (float*)(smem + 8192);
  u16x8* CF = (u16x8*)(smem + 32768);
  unsigned short* CFs = (unsigned short*)(smem + 32768);
  float* QK = (float*)(smem + 45056);
  u16x8* SEF = (u16x8*)(smem + 45056);
  float* SC = (float*)(smem + 53248);

  const int tid = threadIdx.x;
  const int lane = tid & 63, wave = tid >> 6;
  const int lo = lane & 15, q = lane >> 4;
  const int bbase = blockIdx.x * 32;

  // ---- early global loads for phases A / C1 (held in VGPRs across env) ----
  const int bl8 = tid >> 3, n8 = tid & 7;
  const float* s2p = s2 + ((size_t)(bbase + bl8) * 8 + n8) * 7;
  const f32x4u x03 = *(const f32x4u*)s2p;
  const f32x2u x45 = *(const f32x2u*)(s2p + 4);
  const float x6 = s2p[6];
  const float* s0p = s0 + (size_t)(bbase + bl8) * 6;
  const f32x4u y03 = *(const f32x4u*)s0p;
  const f32x2u y45 = *(const f32x2u*)(s0p + 4);

  // ---- env GEMM: env_e = relu(state1 @ Wg + bg), LDS-streamed (R2-verified) ----
  {
    const int mt = wave & 1, ntb = wave >> 1;  // m-tile, n-pair
    const char* s1b = (const char*)(s1 + (size_t)bbase * 1024);

    // staging geometry: thread stages 4x16B per chunk; LDS dest is linear
    // (wave-uniform base + lane*16, required by global_load_lds), global
    // source carries the inverse swizzle: col ^= (row&7)<<4 within the row.
    int srow[4], scol[4];
#pragma unroll
    for (int i = 0; i < 4; ++i) {
      const int T = (i * 256 + tid) * 16;
      srow[i] = T >> 9;
      scol[i] = (T & 511) ^ ((srow[i] & 7) << 4);
    }
    auto stage = [&](char* dst, int c) {
      const int srcb = c * 512;  // chunk base within the 4096 B row
#pragma unroll
      for (int i = 0; i < 4; ++i)
        gload_lds16(s1b + (size_t)srow[i] * 4096 + srcb + scol[i],
                    dst + (i * 256 + tid) * 16);
    };

    f32x4 acc0 = {}, acc1 = {};
    const int row = mt * 16 + lo;
    const int sw = (row & 7) << 4;
    const u16x8* wgfp = (const u16x8*)wgf + (ntb * 2) * 64 + lane;

    auto compute = [&](const char* src, int c) {
#pragma unroll
      for (int kt = 0; kt < 4; ++kt) {
        const int base = row * 512 + kt * 128 + q * 32;
        const f32x4 alo = *(const f32x4*)(src + (base ^ sw));
        const f32x4 ahi = *(const f32x4*)(src + ((base + 16) ^ sw));
        const int ktg = c * 4 + kt;
        const u16x8 b0 = wgfp[(ktg * 4 + 0) * 64];
        const u16x8 b1 = wgfp[(ktg * 4 + 1) * 64];
        const u16x8 af = cvt8(alo, ahi);
        acc0 = mfma16(af, b0, acc0);
        acc1 = mfma16(af, b1, acc1);
      }
    };

    stage(smem, 0);
    __syncthreads();
#pragma unroll
    for (int cc = 0; cc < 4; ++cc) {
      stage(smem + 16384, cc * 2 + 1);  // next chunk in flight across compute
      compute(smem, cc * 2);
      __syncthreads();                  // drains vmcnt: buf1 ready
      if (cc < 3) stage(smem, cc * 2 + 2);
      compute(smem + 16384, cc * 2 + 1);
      __syncthreads();                  // buf0 ready (or: staging region free)
    }

    // epilogue: bias+relu -> concat frags kt 2,3 (A-frag scalar writes;
    // wave (mt,ntb) owns rows mt*16+q*4+ri, cols (ntb*2+ni)*16+lo -> bijective)
#pragma unroll
    for (int ni = 0; ni < 2; ++ni) {
      const f32x4 a = ni ? acc1 : acc0;
      const int h = (ntb * 2 + ni) * 16 + lo;  // concat-col within env block
      const float bias = bg[h];
#pragma unroll
      for (int ri = 0; ri < 4; ++ri) {
        const float v = fmaxf(a[ri] + bias, 0.f);
        CFs[((mt * 6 + 2 + (h >> 5)) * 64 +
             ((((h >> 3) & 3) << 4) | (q * 4 + ri))) * 8 + (h & 7)] = f2bf_u(v);
      }
    }
  }
  // (no barrier needed: env loop's final __syncthreads fenced the staging
  //  reads; epilogue writes CF, phase A writes EF -- disjoint regions)

  // ---- Phase A: E1 = relu(state2 @ Ws1 + bs1), K=7 fp32 VALU; mask ----
  bool maskreg;
  {
    float xv[7] = {x03[0], x03[1], x03[2], x03[3], x45[0], x45[1], x6};
    const float sum = xv[0] + xv[1] + xv[2] + xv[3] + xv[4] + xv[5] + xv[6];
    maskreg = (sum != 0.f);  // padded slots are exact zeros
    const int mt = tid >> 4, rl = tid & 15;
#pragma unroll
    for (int c = 0; c < 8; ++c) {
      float a[8];
#pragma unroll
      for (int i = 0; i < 8; ++i) a[i] = bs1[c * 8 + i];
#pragma unroll
      for (int j = 0; j < 7; ++j) {
        const float* wr = Ws1 + j * 64 + c * 8;
#pragma unroll
        for (int i = 0; i < 8; ++i) a[i] = fmaf(xv[j], wr[i], a[i]);
      }
      u16x8 pk;
#pragma unroll
      for (int i = 0; i < 8; ++i) pk[i] = f2bf_u(fmaxf(a[i], 0.f));
      EF[(mt * 2 + (c >> 2)) * 64 + (((c & 3) << 4) | rl)] = pk;
    }
  }
  __syncthreads();

  // ---- Phase B: E2 = relu(E1 @ Ws2 + bs2), MFMA, in-place frag overwrite ----
  {
    u16x8 Bf[4][2];
#pragma unroll
    for (int nt = 0; nt < 4; ++nt)
#pragma unroll
      for (int kt = 0; kt < 2; ++kt)
        Bf[nt][kt] = ((const u16x8*)ws2f)[(kt * 4 + nt) * 64 + lane];
    float bias[4];
#pragma unroll
    for (int nt = 0; nt < 4; ++nt) bias[nt] = bs2[nt * 16 + lo];
#pragma unroll
    for (int mi = 0; mi < 4; ++mi) {  // wave owns mtiles wave*4..+3
      const int mt = wave * 4 + mi;
      const u16x8 A0 = EF[(mt * 2 + 0) * 64 + lane];
      const u16x8 A1 = EF[(mt * 2 + 1) * 64 + lane];
      f32x4 acc[4] = {};
#pragma unroll
      for (int nt = 0; nt < 4; ++nt) {
        acc[nt] = mfma16(A0, Bf[nt][0], acc[nt]);
        acc[nt] = mfma16(A1, Bf[nt][1], acc[nt]);
      }
#pragma unroll
      for (int nt = 0; nt < 4; ++nt) {
        const int h = nt * 16 + lo;
#pragma unroll
        for (int ri = 0; ri < 4; ++ri) {
          const float v = fmaxf(acc[nt][ri] + bias[nt], 0.f);
          const int rr = mt * 16 + q * 4 + ri;
          EFs[((mt * 2 + (h >> 5)) * 64 + ((((h >> 3) & 3) << 4) | (rr & 15))) * 8 +
              (h & 7)] = f2bf_u(v);
        }
      }
    }
  }
  __syncthreads();

  // ---- Phase C1: own_e = relu(s0 @ W0 + b0), K=6 VALU -> concat kt 0,1 ----
  {
    const int mt = bl8 >> 4, fl = ((n8 & 3) << 4) | (bl8 & 15), kt = n8 >> 2;
    const float yv[6] = {y03[0], y03[1], y03[2], y03[3], y45[0], y45[1]};
    float a[8];
#pragma unroll
    for (int i = 0; i < 8; ++i) a[i] = b0v[n8 * 8 + i];
#pragma unroll
    for (int j = 0; j < 6; ++j) {
      const float* wr = W0 + j * 64 + n8 * 8;
#pragma unroll
      for (int i = 0; i < 8; ++i) a[i] = fmaf(yv[j], wr[i], a[i]);
    }
    u16x8 pk;
#pragma unroll
    for (int i = 0; i < 8; ++i) pk[i] = f2bf_u(fmaxf(a[i], 0.f));
    CF[(mt * 6 + kt) * 64 + fl] = pk;
  }
  __syncthreads();

  // ---- Phase C2: qk = own_e @ M_qk (MFMA) -> QK fp32 [32][64] ----
  {
#pragma unroll
    for (int pp = 0; pp < 2; ++pp) {
      const int pr = wave * 2 + pp, mt = pr >> 2, nt = pr & 3;
      const u16x8 A0 = CF[(mt * 6 + 0) * 64 + lane];
      const u16x8 A1 = CF[(mt * 6 + 1) * 64 + lane];
      const u16x8 B0 = ((const u16x8*)mqkf)[(0 * 4 + nt) * 64 + lane];
      const u16x8 B1 = ((const u16x8*)mqkf)[(1 * 4 + nt) * 64 + lane];
      f32x4 acc = {};
      acc = mfma16(A0, B0, acc);
      acc = mfma16(A1, B1, acc);
#pragma unroll
      for (int ri = 0; ri < 4; ++ri)
        QK[(mt * 16 + q * 4 + ri) * 64 + nt * 16 + lo] = acc[ri];
    }
  }
  __syncthreads();

  // ---- Phase C3: score_r = (E2_r . qk_b)/8, masked -> SC ----
  {
    const int r = tid, bl = r >> 3, mt = r >> 4, rl = r & 15;
    float dot = 0.f;
#pragma unroll
    for (int c = 0; c < 8; ++c) {
      const u16x8 e = EF[(mt * 2 + (c >> 2)) * 64 + (((c & 3) << 4) | rl)];
      const float* qkp = QK + bl * 64 + c * 8;
      const f32x4 qa = *(const f32x4*)(qkp);
      const f32x4 qb = *(const f32x4*)(qkp + 4);
#pragma unroll
      for (int i = 0; i < 4; ++i) dot = fmaf(bfu2f(e[i]), qa[i], dot);
#pragma unroll
      for (int i = 0; i < 4; ++i) dot = fmaf(bfu2f(e[4 + i]), qb[i], dot);
    }
    SC[r] = maskreg ? dot * 0.125f : -1e30f;  // 1/sqrt(64)
  }
  __syncthreads();

  // ---- Phase C4: softmax over N=8, in place in SC ----
  if (tid < 32) {
    float s[8];
#pragma unroll
    for (int n = 0; n < 8; ++n) s[n] = SC[tid * 8 + n];
    float mx = s[0];
#pragma unroll
    for (int n = 1; n < 8; ++n) mx = fmaxf(mx, s[n]);
    float e[8], sum = 0.f;
#pragma unroll
    for (int n = 0; n < 8; ++n) { e[n] = __expf(s[n] - mx); sum += e[n]; }
    const float inv = 1.f / sum;
#pragma unroll
    for (int n = 0; n < 8; ++n) SC[tid * 8 + n] = e[n] * inv;
  }
  __syncthreads();

  // ---- Phase C5: sE2_b = sum_n alpha_n * E2_{b,n} -> SEF frags ----
  {
    float al[8];
#pragma unroll
    for (int n = 0; n < 8; ++n) al[n] = SC[bl8 * 8 + n];
    float a[8] = {0.f, 0.f, 0.f, 0.f, 0.f, 0.f, 0.f, 0.f};
#pragma unroll
    for (int n = 0; n < 8; ++n) {
      const int rr = bl8 * 8 + n;
      const u16x8 e =
          EF[((rr >> 4) * 2 + (n8 >> 2)) * 64 + (((n8 & 3) << 4) | (rr & 15))];
#pragma unroll
      for (int i = 0; i < 8; ++i) a[i] = fmaf(al[n], bfu2f(e[i]), a[i]);
    }
    u16x8 pk;
#pragma unroll
    for (int i = 0; i < 8; ++i) pk[i] = f2bf_u(a[i]);
    SEF[((bl8 >> 4) * 2 + (n8 >> 2)) * 64 + (((n8 & 3) << 4) | (bl8 & 15))] = pk;
  }
  __syncthreads();

  // ---- Phase C6: v_att = sE2 @ Wv (MFMA) -> concat frags kt 4,5 ----
  {
#pragma unroll
    for (int pp = 0; pp < 2; ++pp) {
      const int pr = wave * 2 + pp, mt = pr >> 2, nt = pr & 3;
      const u16x8 A0 = SEF[(mt * 2 + 0) * 64 + lane];
      const u16x8 A1 = SEF[(mt * 2 + 1) * 64 + lane];
      const u16x8 B0 = ((const u16x8*)wvf)[(0 * 4 + nt) * 64 + lane];
      const u16x8 B1 = ((const u16x8*)wvf)[(1 * 4 + nt) * 64 + lane];
      f32x4 acc = {};
      acc = mfma16(A0, B0, acc);
      acc = mfma16(A1, B1, acc);
      const int h = nt * 16 + lo;
#pragma unroll
      for (int ri = 0; ri < 4; ++ri) {
        const int rr = mt * 16 + q * 4 + ri;
        CFs[((mt * 6 + 4 + (h >> 5)) * 64 + ((((h >> 3) & 3) << 4) | (rr & 15))) * 8 +
            (h & 7)] = f2bf_u(acc[ri]);
      }
    }
  }
  __syncthreads();

  // ---- Phase D1: h1 = relu(concat @ Wc1 + bc1), K=192 -> H1F frags ----
  {
    const int mt = wave & 1, ntb = (wave >> 1) * 4;
    u16x8 A[6];
#pragma unroll
    for (int kt = 0; kt < 6; ++kt) A[kt] = CF[(mt * 6 + kt) * 64 + lane];
#pragma unroll
    for (int ni = 0; ni < 4; ++ni) {
      const int nt = ntb + ni;
      f32x4 acc = {};
#pragma unroll
      for (int kt = 0; kt < 6; ++kt) {
        const u16x8 Bf = ((const u16x8*)wc1f)[(kt * 8 + nt) * 64 + lane];
        acc = mfma16(A[kt], Bf, acc);
      }
      const float bias = bc1[nt * 16 + lo];
      const int h = nt * 16 + lo;
#pragma unroll
      for (int ri = 0; ri < 4; ++ri) {
        const float v = fmaxf(acc[ri] + bias, 0.f);
        const int rr = mt * 16 + q * 4 + ri;
        H1Fs[((mt * 4 + (h >> 5)) * 64 + ((((h >> 3) & 3) << 4) | (rr & 15))) * 8 +
             (h & 7)] = f2bf_u(v);
      }
    }
  }
  __syncthreads();

  // ---- Phase D2: h2 = relu(h1 @ Wc2 + bc2) -> H2 fp32 [32][132] ----
  {
    const int mt = wave & 1, ntb = (wave >> 1) * 4;
    u16x8 A[4];
#pragma unroll
    for (int kt = 0; kt < 4; ++kt) A[kt] = H1F[(mt * 4 + kt) * 64 + lane];
#pragma unroll
    for (int ni = 0; ni < 4; ++ni) {
      const int nt = ntb + ni;
      f32x4 acc = {};
#pragma unroll
      for (int kt = 0; kt < 4; ++kt) {
        const u16x8 Bf = ((const u16x8*)wc2f)[(kt * 8 + nt) * 64 + lane];
        acc = mfma16(A[kt], Bf, acc);
      }
      const float bias = bc2[nt * 16 + lo];
#pragma unroll
      for (int ri = 0; ri < 4; ++ri)
        H2[(mt * 16 + q * 4 + ri) * 132 + nt * 16 + lo] =
            fmaxf(acc[ri] + bias, 0.f);
    }
  }
  __syncthreads();

  // ---- Phase D3: out = tanh(h2 @ Wc3 + bc3), fp32, all 256 threads ----
  {
    const int kq = n8 >> 1, a = n8 & 1;  // 4 K-quarters x 2 actions per row
    const f32x4* h4 = (const f32x4*)(H2 + bl8 * 132 + kq * 32);
    const float* wr = Wc3 + kq * 64;  // Wc3[h][2], h = kq*32 + j
    float acc = 0.f;
#pragma unroll
    for (int j4 = 0; j4 < 8; ++j4) {
      const f32x4 hv = h4[j4];
#pragma unroll
      for (int e = 0; e < 4; ++e) acc = fmaf(hv[e], wr[(j4 * 4 + e) * 2 + a], acc);
    }
    acc += __shfl_down(acc, 2);
    acc += __shfl_down(acc, 4);
    if (kq == 0) out[(size_t)(bbase + bl8) * 2 + a] = tanhf(acc + bc3[a]);
  }
}

// ---------------------------------------------------------------------------
extern "C" void kernel_launch(void* const* d_in, const int* in_sizes, int n_in,
                              void* d_out, int out_size, void* d_ws, size_t ws_size,
                              hipStream_t stream) {
  const float* s0  = (const float*)d_in[0];
  const float* s1  = (const float*)d_in[1];
  const float* s2  = (const float*)d_in[2];
  const float* W0  = (const float*)d_in[3];
  const float* b0  = (const float*)d_in[4];
  const float* Wg  = (const float*)d_in[5];
  const float* bg  = (const float*)d_in[6];
  const float* Ws1 = (const float*)d_in[7];
  const float* bs1 = (const float*)d_in[8];
  const float* Ws2 = (const float*)d_in[9];
  const float* bs2 = (const float*)d_in[10];
  const float* Wq  = (const float*)d_in[11];
  const float* Wk  = (const float*)d_in[12];
  const float* Wv  = (const float*)d_in[13];
  const float* Wc1 = (const float*)d_in[14];
  const float* bc1 = (const float*)d_in[15];
  const float* Wc2 = (const float*)d_in[16];
  const float* bc2 = (const float*)d_in[17];
  const float* Wc3 = (const float*)d_in[18];
  const float* bc3 = (const float*)d_in[19];

  char* ws = (char*)d_ws;
  unsigned short* wgf  = (unsigned short*)(ws + WS_WGF);
  unsigned short* ws2f = (unsigned short*)(ws + WS_WS2);
  unsigned short* wvf  = (unsigned short*)(ws + WS_WV);
  unsigned short* mqkf = (unsigned short*)(ws + WS_MQK);
  unsigned short* wc1f = (unsigned short*)(ws + WS_WC1);
  unsigned short* wc2f = (unsigned short*)(ws + WS_WC2);

  hipLaunchKernelGGL(k_prep, dim3(464), dim3(256), 0, stream, Wg, Ws2, Wv, Wq,
                     Wk, Wc1, Wc2, wgf, ws2f, wvf, mqkf, wc1f, wc2f);
  hipLaunchKernelGGL(k_main, dim3(2048), dim3(256), 0, stream, s0, s1, s2, W0,
                     b0, wgf, bg, Ws1, bs1, ws2f, bs2, wvf, mqkf, wc1f, bc1,
                     wc2f, bc2, Wc3, bc3, (float*)d_out);
}

// Round 9
// 452.456 us; speedup vs baseline: 1.0404x; 1.0020x over previous
//
#include <hip/hip_runtime.h>
#include <math.h>

// ---------------------------------------------------------------------------
// ActorNetwork forward, MI355X (gfx950). Round 7b: wave-local restructure
// (+ per-wave lgkmcnt fence in env staging, the only delta vs R7).
// R6 falsified the MLP theory (30x in-flight bytes -> identical 163 us).
// Diagnosis: ~20 __syncthreads (each full vmcnt/lgkmcnt drain + sched fence)
// with ~2-3 resident blocks/CU -> stall-dominated (VALU 19%, MFMA 4.7%).
// Wave w owns batch rows w*8..+8 (E-rows w*64..+63): A,B,C3,C5 wave-local;
// own_e/qk computed redundantly per wave (identical values); softmax
// in-register via __shfl (bitwise-identical order); env GEMM per-wave staged
// (global_load_lds -> wave-private 8KB, per-wave vmcnt(0)/lgkmcnt(0); TLP
// provides MLP). Barriers: 20 -> 4. All fragment formulas / accumulation
// orders bit-identical to verified R0/R6 kernels.
// Shapes: B=65536,N=8,OBS0=6,OBS1=1024,OBS2=7,H=64,HC=128,NA=2.
// ---------------------------------------------------------------------------

typedef float f32x4 __attribute__((ext_vector_type(4)));
typedef float f32x4u __attribute__((ext_vector_type(4), aligned(4)));
typedef float f32x2u __attribute__((ext_vector_type(2), aligned(4)));
typedef __bf16 bf16x8 __attribute__((ext_vector_type(8)));
typedef unsigned short u16x8 __attribute__((ext_vector_type(8)));

#define DI __device__ __forceinline__

DI unsigned short f2bf_u(float f) {  // fp32 -> bf16 bits, RTNE
  unsigned u = __builtin_bit_cast(unsigned, f);
  u += 0x7fffu + ((u >> 16) & 1u);
  return (unsigned short)(u >> 16);
}
DI float bfu2f(unsigned short s) {
  unsigned u = ((unsigned)s) << 16;
  return __builtin_bit_cast(float, u);
}
DI u16x8 cvt8(f32x4 x, f32x4 y) {
  bf16x8 r;
  r[0] = (__bf16)x[0]; r[1] = (__bf16)x[1]; r[2] = (__bf16)x[2]; r[3] = (__bf16)x[3];
  r[4] = (__bf16)y[0]; r[5] = (__bf16)y[1]; r[6] = (__bf16)y[2]; r[7] = (__bf16)y[3];
  return __builtin_bit_cast(u16x8, r);
}
DI f32x4 mfma16(u16x8 a, u16x8 b, f32x4 c) {
  return __builtin_amdgcn_mfma_f32_16x16x32_bf16(
      __builtin_bit_cast(bf16x8, a), __builtin_bit_cast(bf16x8, b), c, 0, 0, 0);
}
DI void gload_lds16(const void* g, void* l) {  // async global->LDS, 16 B/lane
  typedef __attribute__((address_space(1))) const unsigned GU;
  typedef __attribute__((address_space(3))) unsigned LU;
  __builtin_amdgcn_global_load_lds((GU*)g, (LU*)l, 16, 0, 0);
}

// Fragment layouts (learn_hip m89/m91):
//   A-frag: lane l holds A[m = l&15][k = (l>>4)*8 + j], j=0..7
//   B-frag: lane l holds B[k = (l>>4)*8 + j][n = l&15]
//   C/D   : lane l holds C[row = (l>>4)*4 + ri][col = l&15]

// ---- workspace layout (bytes) ----
constexpr size_t WS_WGF = 0;        // Wg frags  [32kt][4nt]   131072
constexpr size_t WS_WS2 = 131072;   // Ws2 frags [2][4]          8192
constexpr size_t WS_WV  = 139264;   // Wv frags  [2][4]          8192
constexpr size_t WS_MQK = 147456;   // Mqk frags [2][4]          8192
constexpr size_t WS_WC1 = 155648;   // Wc1 frags [6][8]         49152
constexpr size_t WS_WC2 = 204800;   // Wc2 frags [4][8]         32768

// ---------------------------------------------------------------------------
// k_prep: pack all weights into bf16 B-frag layout; M_qk computed inline.
// ---------------------------------------------------------------------------
__global__ __launch_bounds__(256) void k_prep(
    const float* __restrict__ Wg, const float* __restrict__ Ws2,
    const float* __restrict__ Wv, const float* __restrict__ Wq,
    const float* __restrict__ Wk, const float* __restrict__ Wc1,
    const float* __restrict__ Wc2,
    unsigned short* __restrict__ wgf, unsigned short* __restrict__ ws2f,
    unsigned short* __restrict__ wvf, unsigned short* __restrict__ mqkf,
    unsigned short* __restrict__ wc1f, unsigned short* __restrict__ wc2f) {
  const int idx = blockIdx.x * 256 + threadIdx.x;  // 118784 total
  const float* src = nullptr;
  unsigned short* dst;
  int i, ntm, NC;
  bool is_mqk = false;
  if (idx < 65536)      { src = Wg;  dst = wgf;  i = idx;          ntm = 2; NC = 64;  }
  else if (idx < 69632) { src = Ws2; dst = ws2f; i = idx - 65536;  ntm = 2; NC = 64;  }
  else if (idx < 73728) { src = Wv;  dst = wvf;  i = idx - 69632;  ntm = 2; NC = 64;  }
  else if (idx < 77824) { is_mqk = true; dst = mqkf; i = idx - 73728; ntm = 2; NC = 64; }
  else if (idx < 102400){ src = Wc1; dst = wc1f; i = idx - 77824;  ntm = 3; NC = 128; }
  else                  { src = Wc2; dst = wc2f; i = idx - 102400; ntm = 3; NC = 128; }
  const int j = i & 7, ln = (i >> 3) & 63, t2 = i >> 9;
  const int nt = t2 & ((1 << ntm) - 1), kt = t2 >> ntm;
  const int k = kt * 32 + (ln >> 4) * 8 + j, n = nt * 16 + (ln & 15);
  float val;
  if (is_mqk) {  // M_qk[k][n] = dot(Wq[k,:], Wk[n,:])
    const f32x4* qp = (const f32x4*)(Wq + k * 64);
    const f32x4* kp = (const f32x4*)(Wk + n * 64);
    float acc = 0.f;
#pragma unroll
    for (int d4 = 0; d4 < 16; ++d4) {
      const f32x4 a = qp[d4], b = kp[d4];
#pragma unroll
      for (int e = 0; e < 4; ++e) acc = fmaf(a[e], b[e], acc);
    }
    val = acc;
  } else {
    val = src[k * NC + n];
  }
  dst[i] = f2bf_u(val);
}

// ---------------------------------------------------------------------------
// k_main: 32 batch rows / block, 2048 blocks x 256 thr, 4 barriers total.
// ---------------------------------------------------------------------------
__global__ __launch_bounds__(256, 3) void k_main(
    const float* __restrict__ s0, const float* __restrict__ s1,
    const float* __restrict__ s2,
    const float* __restrict__ W0, const float* __restrict__ b0v,
    const unsigned short* __restrict__ wgf, const float* __restrict__ bg,
    const float* __restrict__ Ws1, const float* __restrict__ bs1,
    const unsigned short* __restrict__ ws2f, const float* __restrict__ bs2,
    const unsigned short* __restrict__ wvf, const unsigned short* __restrict__ mqkf,
    const unsigned short* __restrict__ wc1f, const float* __restrict__ bc1,
    const unsigned short* __restrict__ wc2f, const float* __restrict__ bc2,
    const float* __restrict__ Wc3, const float* __restrict__ bc3,
    float* __restrict__ out) {
  // LDS map (53760 B -> 3 blocks/CU):
  //  [0,32768)     EF: E1/E2 frags [16mt][2kt][64] u16x8 (wave w owns bytes
  //                w*8192..+8192); env staging (8KB/wave) overlays own region;
  //                later H1F [2][4][64] (0..8192) + H2 fp32 [32][132] @+8192
  //  [32768,40960) CF: u16x8 [2mt][4kt][64]  (kt 0,1 = env_e; 2,3 = v_att)
  //  [40960,49664) QK: fp32 [32][68] (padded); RED f32x4 [2][4][64] pre-C2
  //  [49664,53760) SEF: u16x8 [2][2][64]
  __shared__ __align__(16) char smem[53760];
  u16x8* EF = (u16x8*)smem;
  unsigned short* EFs = (unsigned short*)smem;
  u16x8* H1F = (u16x8*)smem;
  unsigned short* H1Fs = (unsigned short*)smem;
  float* H2 = (float*)(smem + 8192);
  u16x8* CF = (u16x8*)(smem + 32768);
  unsigned short* CFs = (unsigned short*)(smem + 32768);
  float* QKf = (float*)(smem + 40960);
  f32x4* RED = (f32x4*)(smem + 40960);
  u16x8* SEF = (u16x8*)(smem + 49664);

  const int tid = threadIdx.x;
  const int lane = tid & 63, wave = tid >> 6;
  const int lo = lane & 15, q = lane >> 4;
  const int bbase = blockIdx.x * 32;
  const int bl8 = tid >> 3, n8 = tid & 7;
  const int mt_q = wave >> 1;  // m-tile ownership for C/D phases

  // ---- early global loads for phase A (held across env) ----
  const float* s2p = s2 + ((size_t)(bbase + bl8) * 8 + n8) * 7;
  const f32x4u x03 = *(const f32x4u*)s2p;
  const f32x2u x45 = *(const f32x2u*)(s2p + 4);
  const float x6 = s2p[6];

  // ---- env GEMM: per-wave staged, split-K; wave w: mt=w&1, K-half=w>>1 ----
  {
    const int mt_e = wave & 1, kh = wave >> 1;
    char* sbuf = smem + wave * 8192;  // wave-private; == own EF region (serial)
    const char* s1b = (const char*)s1 + (size_t)(bbase + mt_e * 16) * 4096 + kh * 2048;
    const u16x8* wg8 = (const u16x8*)wgf;
    f32x4 acc[4] = {};
    const int sw = (lo & 7) << 4;
    for (int c = 0; c < 4; ++c) {  // 4 chunks of 128 cols (16 rows x 512 B)
      if (c) {  // fence: this wave's ds_reads of chunk c-1 must complete
        asm volatile("s_waitcnt lgkmcnt(0)" ::: "memory");
      }
#pragma unroll
      for (int i = 0; i < 8; ++i) {  // LDS dest linear; source pre-swizzled
        const int T = (i * 64 + lane) * 16;
        const int rw = T >> 9, cb = T & 511;
        gload_lds16(s1b + (size_t)rw * 4096 + c * 512 + (cb ^ ((rw & 7) << 4)),
                    sbuf + T);
      }
      asm volatile("s_waitcnt vmcnt(0)" ::: "memory");  // per-wave wait
#pragma unroll
      for (int kt = 0; kt < 4; ++kt) {
        const int base = lo * 512 + kt * 128 + q * 32;
        const f32x4 alo = *(const f32x4*)(sbuf + (base ^ sw));
        const f32x4 ahi = *(const f32x4*)(sbuf + ((base + 16) ^ sw));
        const int ktg = kh * 16 + c * 4 + kt;
        const u16x8 af = cvt8(alo, ahi);
#pragma unroll
        for (int nt = 0; nt < 4; ++nt)
          acc[nt] = mfma16(af, wg8[(ktg * 4 + nt) * 64 + lane], acc[nt]);
      }
    }
    if (kh == 1) {  // high-half partials -> RED
#pragma unroll
      for (int nt = 0; nt < 4; ++nt) RED[(mt_e * 4 + nt) * 64 + lane] = acc[nt];
    }
    __syncthreads();  // B0 (only cross-wave point of env)
    if (kh == 0) {
      // RED reads are this wave's FIRST post-barrier LDS ops; the QK writes
      // that alias RED happen >=1400cy later in sibling waves (A,B,C1 first)
      // -> no overlap (post-barrier issue skew is tens of cycles).
#pragma unroll
      for (int nt = 0; nt < 4; ++nt) {
        const f32x4 a = acc[nt] + RED[(mt_e * 4 + nt) * 64 + lane];
        const int h = nt * 16 + lo;
        const float bias = bg[h];
#pragma unroll
        for (int ri = 0; ri < 4; ++ri) {
          const float v = fmaxf(a[ri] + bias, 0.f);
          CFs[((mt_e * 4 + (h >> 5)) * 64 +
               ((((h >> 3) & 3) << 4) | (q * 4 + ri))) * 8 + (h & 7)] = f2bf_u(v);
        }
      }
    }
  }

  // ---- Phase A: E1 = relu(state2 @ Ws1 + bs1) -> EF (wave-local region) ----
  bool maskreg;
  {
    float xv[7] = {x03[0], x03[1], x03[2], x03[3], x45[0], x45[1], x6};
    const float sum = xv[0] + xv[1] + xv[2] + xv[3] + xv[4] + xv[5] + xv[6];
    maskreg = (sum != 0.f);  // padded slots are exact zeros
    const int mt = tid >> 4, rl = tid & 15;
#pragma unroll
    for (int c = 0; c < 8; ++c) {
      float a[8];
#pragma unroll
      for (int i = 0; i < 8; ++i) a[i] = bs1[c * 8 + i];
#pragma unroll
      for (int j = 0; j < 7; ++j) {
        const float* wr = Ws1 + j * 64 + c * 8;
#pragma unroll
        for (int i = 0; i < 8; ++i) a[i] = fmaf(xv[j], wr[i], a[i]);
      }
      u16x8 pk;
#pragma unroll
      for (int i = 0; i < 8; ++i) pk[i] = f2bf_u(fmaxf(a[i], 0.f));
      EF[(mt * 2 + (c >> 2)) * 64 + (((c & 3) << 4) | rl)] = pk;
    }
  }
  // no barrier: E-rows tid are produced and consumed by the same wave

  // ---- Phase B: E2 = relu(E1 @ Ws2 + bs2), wave-local in-place ----
  {
    const u16x8* w2 = (const u16x8*)ws2f;
    u16x8 Bf[4][2];
#pragma unroll
    for (int nt = 0; nt < 4; ++nt)
#pragma unroll
      for (int kt = 0; kt < 2; ++kt) Bf[nt][kt] = w2[(kt * 4 + nt) * 64 + lane];
    float bias[4];
#pragma unroll
    for (int nt = 0; nt < 4; ++nt) bias[nt] = bs2[nt * 16 + lo];
#pragma unroll
    for (int mi = 0; mi < 4; ++mi) {
      const int mt = wave * 4 + mi;
      const u16x8 A0 = EF[(mt * 2 + 0) * 64 + lane];
      const u16x8 A1 = EF[(mt * 2 + 1) * 64 + lane];
      f32x4 acc[4] = {};
#pragma unroll
      for (int nt = 0; nt < 4; ++nt) {
        acc[nt] = mfma16(A0, Bf[nt][0], acc[nt]);
        acc[nt] = mfma16(A1, Bf[nt][1], acc[nt]);
      }
#pragma unroll
      for (int nt = 0; nt < 4; ++nt) {
        const int h = nt * 16 + lo;
#pragma unroll
        for (int ri = 0; ri < 4; ++ri) {
          const float v = fmaxf(acc[nt][ri] + bias[nt], 0.f);
          const int rr = mt * 16 + q * 4 + ri;
          EFs[((mt * 2 + (h >> 5)) * 64 + ((((h >> 3) & 3) << 4) | (rr & 15))) * 8 +
              (h & 7)] = f2bf_u(v);
        }
      }
    }
  }
  // no barrier: wave-local

  // ---- C1: own_e redundant per wave, DIRECTLY in A-frag registers ----
  u16x8 cf0, cf1;
  {
    const float* s0r = s0 + (size_t)(bbase + mt_q * 16 + lo) * 6;
    float yv[6];
#pragma unroll
    for (int j = 0; j < 6; ++j) yv[j] = s0r[j];
#pragma unroll
    for (int half = 0; half < 2; ++half) {
      const int cb = half * 32 + q * 8;
      float a[8];
#pragma unroll
      for (int i = 0; i < 8; ++i) a[i] = b0v[cb + i];
#pragma unroll
      for (int j = 0; j < 6; ++j) {
        const float* wr = W0 + j * 64 + cb;
#pragma unroll
        for (int i = 0; i < 8; ++i) a[i] = fmaf(yv[j], wr[i], a[i]);
      }
      u16x8 pk;
#pragma unroll
      for (int i = 0; i < 8; ++i) pk[i] = f2bf_u(fmaxf(a[i], 0.f));
      if (half) cf1 = pk; else cf0 = pk;
    }
  }

  // ---- C2: qk = own_e @ M_qk, redundant per wave -> QK (dup-identical) ----
  {
    const u16x8* mq8 = (const u16x8*)mqkf;
#pragma unroll
    for (int nt = 0; nt < 4; ++nt) {
      f32x4 acc = {};
      acc = mfma16(cf0, mq8[(0 * 4 + nt) * 64 + lane], acc);
      acc = mfma16(cf1, mq8[(1 * 4 + nt) * 64 + lane], acc);
#pragma unroll
      for (int ri = 0; ri < 4; ++ri)
        QKf[(mt_q * 16 + q * 4 + ri) * 68 + nt * 16 + lo] = acc[ri];
    }
  }
  // no barrier: this wave reads back only rows it wrote (sibling dup benign)

  // ---- C3: score = (E2_r . qk_b)/8, masked -> register ----
  float score;
  {
    const int r = tid, mt = r >> 4, rl = r & 15;
    float dot = 0.f;
#pragma unroll
    for (int c = 0; c < 8; ++c) {
      const u16x8 e = EF[(mt * 2 + (c >> 2)) * 64 + (((c & 3) << 4) | rl)];
      const float* qkp = QKf + bl8 * 68 + c * 8;
      const f32x4 qa = *(const f32x4*)(qkp);
      const f32x4 qb = *(const f32x4*)(qkp + 4);
#pragma unroll
      for (int i = 0; i < 4; ++i) dot = fmaf(bfu2f(e[i]), qa[i], dot);
#pragma unroll
      for (int i = 0; i < 4; ++i) dot = fmaf(bfu2f(e[4 + i]), qb[i], dot);
    }
    score = maskreg ? dot * 0.125f : -1e30f;  // 1/sqrt(64)
  }

  // ---- C4: softmax over N=8 fully in registers (shfl gather; sequential
  //      max/sum order -> bitwise identical to the LDS version) ----
  float al[8];
  {
    const int gb = lane & 56;
    float sv[8];
#pragma unroll
    for (int n = 0; n < 8; ++n) sv[n] = __shfl(score, gb + n, 64);
    float mx = sv[0];
#pragma unroll
    for (int n = 1; n < 8; ++n) mx = fmaxf(mx, sv[n]);
    float ex[8], sum = 0.f;
#pragma unroll
    for (int n = 0; n < 8; ++n) { ex[n] = __expf(sv[n] - mx); sum += ex[n]; }
    const float inv = 1.f / sum;
#pragma unroll
    for (int n = 0; n < 8; ++n) al[n] = ex[n] * inv;
  }

  // ---- C5: sE2_b = sum_n alpha_n * E2_{b,n} -> SEF frags (wave-local EF) ----
  {
    float a[8] = {0.f, 0.f, 0.f, 0.f, 0.f, 0.f, 0.f, 0.f};
#pragma unroll
    for (int n = 0; n < 8; ++n) {
      const int rr = bl8 * 8 + n;
      const u16x8 e =
          EF[((rr >> 4) * 2 + (n8 >> 2)) * 64 + (((n8 & 3) << 4) | (rr & 15))];
#pragma unroll
      for (int i = 0; i < 8; ++i) a[i] = fmaf(al[n], bfu2f(e[i]), a[i]);
    }
    u16x8 pk;
#pragma unroll
    for (int i = 0; i < 8; ++i) pk[i] = f2bf_u(a[i]);
    SEF[((bl8 >> 4) * 2 + (n8 >> 2)) * 64 + (((n8 & 3) << 4) | (bl8 & 15))] = pk;
  }
  __syncthreads();  // B1: SEF frag rows span both waves of an mt pair

  // ---- C6: v_att = sE2 @ Wv, redundant per wave -> CF kt 2,3 ----
  {
    const u16x8* wv8 = (const u16x8*)wvf;
    const u16x8 A0 = SEF[(mt_q * 2 + 0) * 64 + lane];
    const u16x8 A1 = SEF[(mt_q * 2 + 1) * 64 + lane];
#pragma unroll
    for (int nt = 0; nt < 4; ++nt) {
      f32x4 acc = {};
      acc = mfma16(A0, wv8[(0 * 4 + nt) * 64 + lane], acc);
      acc = mfma16(A1, wv8[(1 * 4 + nt) * 64 + lane], acc);
      const int h = nt * 16 + lo;
#pragma unroll
      for (int ri = 0; ri < 4; ++ri)
        CFs[((mt_q * 4 + 2 + (h >> 5)) * 64 +
             ((((h >> 3) & 3) << 4) | (q * 4 + ri))) * 8 + (h & 7)] =
            f2bf_u(acc[ri]);
    }
  }
  // no barrier: D1 reads this wave's own writes (sibling dup identical;
  // env kt 0,1 fenced by B0/B1)

  // ---- D1: h1 = relu(concat @ Wc1 + bc1), K=192 (own=regs, env/vatt=CF) ----
  {
    const int ntb = (wave & 1) * 4;
    const u16x8* w18 = (const u16x8*)wc1f;
    u16x8 A2[4];
#pragma unroll
    for (int kt = 0; kt < 4; ++kt) A2[kt] = CF[(mt_q * 4 + kt) * 64 + lane];
#pragma unroll
    for (int ni = 0; ni < 4; ++ni) {
      const int nt = ntb + ni;
      f32x4 acc = {};
      acc = mfma16(cf0, w18[(0 * 8 + nt) * 64 + lane], acc);
      acc = mfma16(cf1, w18[(1 * 8 + nt) * 64 + lane], acc);
#pragma unroll
      for (int kt = 0; kt < 4; ++kt)
        acc = mfma16(A2[kt], w18[((2 + kt) * 8 + nt) * 64 + lane], acc);
      const float bias = bc1[nt * 16 + lo];
      const int h = nt * 16 + lo;
#pragma unroll
      for (int ri = 0; ri < 4; ++ri) {
        const float v = fmaxf(acc[ri] + bias, 0.f);
        const int rr = mt_q * 16 + q * 4 + ri;
        H1Fs[((mt_q * 4 + (h >> 5)) * 64 + ((((h >> 3) & 3) << 4) | (rr & 15))) * 8 +
             (h & 7)] = f2bf_u(v);
      }
    }
  }
  __syncthreads();  // B2: H1F kt slots written by both ntb waves of an mt

  // ---- D2: h2 = relu(h1 @ Wc2 + bc2) -> H2 fp32 [32][132] ----
  {
    const int ntb = (wave & 1) * 4;
    const u16x8* w28 = (const u16x8*)wc2f;
    u16x8 A[4];
#pragma unroll
    for (int kt = 0; kt < 4; ++kt) A[kt] = H1F[(mt_q * 4 + kt) * 64 + lane];
#pragma unroll
    for (int ni = 0; ni < 4; ++ni) {
      const int nt = ntb + ni;
      f32x4 acc = {};
#pragma unroll
      for (int kt = 0; kt < 4; ++kt)
        acc = mfma16(A[kt], w28[(kt * 8 + nt) * 64 + lane], acc);
      const float bias = bc2[nt * 16 + lo];
#pragma unroll
      for (int ri = 0; ri < 4; ++ri)
        H2[(mt_q * 16 + q * 4 + ri) * 132 + nt * 16 + lo] =
            fmaxf(acc[ri] + bias, 0.f);
    }
  }
  __syncthreads();  // B3: H2 rows read across waves in D3

  // ---- D3: out = tanh(h2 @ Wc3 + bc3) ----
  {
    const int kq = n8 >> 1, a = n8 & 1;
    const f32x4* h4 = (const f32x4*)(H2 + bl8 * 132 + kq * 32);
    const float* wr = Wc3 + kq * 64;
    float acc = 0.f;
#pragma unroll
    for (int j4 = 0; j4 < 8; ++j4) {
      const f32x4 hv = h4[j4];
#pragma unroll
      for (int e = 0; e < 4; ++e) acc = fmaf(hv[e], wr[(j4 * 4 + e) * 2 + a], acc);
    }
    acc += __shfl_down(acc, 2);
    acc += __shfl_down(acc, 4);
    if (kq == 0) out[(size_t)(bbase + bl8) * 2 + a] = tanhf(acc + bc3[a]);
  }
}

// ---------------------------------------------------------------------------
extern "C" void kernel_launch(void* const* d_in, const int* in_sizes, int n_in,
                              void* d_out, int out_size, void* d_ws, size_t ws_size,
                              hipStream_t stream) {
  const float* s0  = (const float*)d_in[0];
  const float* s1  = (const float*)d_in[1];
  const float* s2  = (const float*)d_in[2];
  const float* W0  = (const float*)d_in[3];
  const float* b0  = (const float*)d_in[4];
  const float* Wg  = (const float*)d_in[5];
  const float* bg  = (const float*)d_in[6];
  const float* Ws1 = (const float*)d_in[7];
  const float* bs1 = (const float*)d_in[8];
  const float* Ws2 = (const float*)d_in[9];
  const float* bs2 = (const float*)d_in[10];
  const float* Wq  = (const float*)d_in[11];
  const float* Wk  = (const float*)d_in[12];
  const float* Wv  = (const float*)d_in[13];
  const float* Wc1 = (const float*)d_in[14];
  const float* bc1 = (const float*)d_in[15];
  const float* Wc2 = (const float*)d_in[16];
  const float* bc2 = (const float*)d_in[17];
  const float* Wc3 = (const float*)d_in[18];
  const float* bc3 = (const float*)d_in[19];

  char* ws = (char*)d_ws;
  unsigned short* wgf  = (unsigned short*)(ws + WS_WGF);
  unsigned short* ws2f = (unsigned short*)(ws + WS_WS2);
  unsigned short* wvf  = (unsigned short*)(ws + WS_WV);
  unsigned short* mqkf = (unsigned short*)(ws + WS_MQK);
  unsigned short* wc1f = (unsigned short*)(ws + WS_WC1);
  unsigned short* wc2f = (unsigned short*)(ws + WS_WC2);

  hipLaunchKernelGGL(k_prep, dim3(464), dim3(256), 0, stream, Wg, Ws2, Wv, Wq,
                     Wk, Wc1, Wc2, wgf, ws2f, wvf, mqkf, wc1f, wc2f);
  hipLaunchKernelGGL(k_main, dim3(2048), dim3(256), 0, stream, s0, s1, s2, W0,
                     b0, wgf, bg, Ws1, bs1, ws2f, bs2, wvf, mqkf, wc1f, bc1,
                     wc2f, bc2, Wc3, bc3, (float*)d_out);
}